// Round 15
// baseline (1079.225 us; speedup 1.0000x reference)
//
#include <hip/hip_runtime.h>

// SPINN v15 = v12 (champion, proven barrier ordering: every arrival at gen
// g+1 is program-ordered after waiting flag g) + v13's provenance staging
// ONLY (seq-sourced sp1/sp2 rows staged pre-wait with plain cached loads;
// only reduce-output rows use post-wait coherent loads). The needA wait
// elision is REMOVED - it broke the root-counter ordering invariant (R13/R14
// deadlocks: a set skipping wait(g) let a subline complete gen g+1 before
// gen g's 4th subline, mis-attributing the root increment; no publish-side
// fix can help). flag publish via fetch_max kept as hardening.

constexpr int NB  = 128;
constexpr int LL  = 32;
constexpr int TT  = 63;
constexpr int NWG = 256;
constexpr int NTH = 512;
constexpr int SROWS = 64;

struct Params {
  const float* seq; const int* trans;
  const float* Wx[4];              // i,o,f,u ; Wx[2]==W_o (ref bug kept)
  const float* Ul[4]; const float* Ur[4];
  const float* bias[4];            // b_i, b_o, b_f, b_u
  const float* tWih; const float* tWhh; const float* tbih; const float* tbhh;
  const float* th0; const float* tc0;
  float* stack; float* tg;
  unsigned* bm;
  float* out;
};

__device__ __forceinline__ float sigm(float x) { return 1.0f / (1.0f + __expf(-x)); }
__device__ __forceinline__ float tanh_f(float x) {
  x = fminf(fmaxf(x, -15.0f), 15.0f);
  float e = __expf(2.0f * x);
  return (e - 1.0f) / (e + 1.0f);
}
__device__ __forceinline__ float cohLoad(const float* a) {
  return __hip_atomic_load(const_cast<float*>(a), __ATOMIC_RELAXED, __HIP_MEMORY_SCOPE_AGENT);
}
__device__ __forceinline__ float4 cohLoad4(const float* a) {
  union { unsigned long long u[2]; float4 f; } r;
  const unsigned long long* p64 = (const unsigned long long*)a;
  r.u[0] = __hip_atomic_load(const_cast<unsigned long long*>(p64),
                             __ATOMIC_RELAXED, __HIP_MEMORY_SCOPE_AGENT);
  r.u[1] = __hip_atomic_load(const_cast<unsigned long long*>(p64 + 1),
                             __ATOMIC_RELAXED, __HIP_MEMORY_SCOPE_AGENT);
  return r.f;
}
__device__ __forceinline__ void cohStore(float* a, float v) {
  __hip_atomic_store(a, v, __ATOMIC_RELAXED, __HIP_MEMORY_SCOPE_AGENT);
}
__device__ __forceinline__ void cohStore2(float* a, float2 v) {
  union { float2 f; unsigned long long u; } r; r.f = v;
  __hip_atomic_store((unsigned long long*)a, r.u, __ATOMIC_RELAXED,
                     __HIP_MEMORY_SCOPE_AGENT);
}
__device__ __forceinline__ void drainvm() {
  asm volatile("s_waitcnt vmcnt(0)" ::: "memory");
}
__device__ __forceinline__ unsigned relAdd(unsigned* a) {
  return __hip_atomic_fetch_add(a, 1u, __ATOMIC_RELAXED, __HIP_MEMORY_SCOPE_AGENT) + 1u;
}
__device__ __forceinline__ void flagMax(unsigned* f, unsigned gen) {
  __hip_atomic_fetch_max(f, gen, __ATOMIC_RELAXED, __HIP_MEMORY_SCOPE_AGENT);
}

__device__ __forceinline__ void barA_arrive(unsigned* blk, unsigned gen, int l) {
  if (threadIdx.x == 0) {
    unsigned a = relAdd(blk + (l & 3) * 32);
    if (a == gen * 8u) {
      unsigned r = relAdd(blk + 128);
      if (r == gen * 4u) flagMax(blk + 160, gen);
    }
  }
}
__device__ __forceinline__ void barB_arrive_lane(unsigned* blk, unsigned gen, int l) {
  unsigned a = relAdd(blk + (l & 3) * 32);
  if (a == gen * 32u) {
    unsigned r = relAdd(blk + 128);
    if (r == gen * 4u) flagMax(blk + 160, gen);
  }
}
__device__ __forceinline__ void bar_wait(unsigned* blk, unsigned gen) {
  if (threadIdx.x == 0) {
    while (__hip_atomic_load(blk + 160, __ATOMIC_RELAXED, __HIP_MEMORY_SCOPE_AGENT) < gen)
      __builtin_amdgcn_s_sleep(1);
  }
  __syncthreads();
}

__launch_bounds__(NTH)
__global__ void spinn_kernel(Params p) {
  const int w = blockIdx.x;
  const int t = threadIdx.x;
  const int cg  = w & 31;
  const int bgp = w >> 5;
  const int b0  = bgp * 16;
  const int nc0 = cg * 16;
  const int o0  = cg * 8;

  unsigned* blkA = p.bm + (size_t)bgp * 512;
  unsigned* blkB = blkA + 256;

  __shared__ float opAll[16][1540];
  __shared__ float th2s[16][68];
  __shared__ float tc2s[16][68];
  __shared__ float accS[4][64][17];
  __shared__ float accR[64][17];
  __shared__ float xS[64][17];
  __shared__ float tbsum[256];
  __shared__ float biasS[4][16];
  __shared__ unsigned char sp1t[TT + 1][16], sp2t[TT + 1][16];
  __shared__ unsigned char sp1sr[TT + 1][16], sp2sr[TT + 1][16];  // 0..31 seq idx, 32 zero, 200 stack
  __shared__ unsigned char buft[TT + 1][16], redt[TT + 1][16];
  __shared__ int anyredt[TT + 1];
  __shared__ int bufSamet[TT + 1];
  __shared__ unsigned char rowSrcS[16][64];
  __shared__ unsigned char qstkS[16][40];

  const int rq = t >> 7;
  const int kb = (t & 127) * 4;

  // ---- prologue
  if (t < 256) tbsum[t] = p.tbih[t] + p.tbhh[t];
  if (t < 64) biasS[t >> 4][t & 15] = p.bias[t >> 4][nc0 + (t & 15)];
  for (int i = t; i < 1024; i += NTH) {
    th2s[i >> 6][i & 63] = p.th0[(size_t)(b0 + (i >> 6)) * 64 + (i & 63)];
    tc2s[i >> 6][i & 63] = p.tc0[(size_t)(b0 + (i >> 6)) * 64 + (i & 63)];
  }
  if (t < 16) {
    buft[0][t] = 255;
    rowSrcS[t][0] = 32;                     // row 0 = zeros
    int bl = t, qn = 0, bp = 0;
    for (int s = 1; s <= TT; ++s) {
      int mask = p.trans[(size_t)(b0 + bl) * TT + (s - 1)];
      int s1 = (qn >= 1) ? qstkS[bl][qn - 1] : 0;
      int s2 = (qn >= 2) ? qstkS[bl][qn - 2] : 0;
      int rd = (mask == 1);
      sp1t[s][bl] = (unsigned char)s1;
      sp2t[s][bl] = (unsigned char)s2;
      sp1sr[s][bl] = rowSrcS[bl][s1];
      sp2sr[s][bl] = rowSrcS[bl][s2];
      redt[s][bl] = (unsigned char)rd;
      int bfv = (bp < LL) ? bp : LL;
      buft[s][bl] = (unsigned char)bfv;
      rowSrcS[bl][s] = rd ? 200 : (unsigned char)((bfv < LL) ? bfv : 32);
      int qn2 = rd ? (qn - 2) : qn;
      qstkS[bl][qn2] = (unsigned char)s;
      qn = qn2 + 1;
      bp += rd ? 0 : 1;
    }
  }
  __syncthreads();
  if (t == 0) {
    for (int s = 1; s <= TT; ++s) {
      int a = 0, same = 1;
      for (int bl = 0; bl < 16; ++bl) {
        a |= redt[s][bl];
        same &= (buft[s][bl] == buft[s - 1][bl]);
      }
      anyredt[s] = a;
      bufSamet[s] = same;
    }
  }
  // zero our 32-col slice of stack row 0 for our 16 b
  {
    int bl = t >> 5, cc = t & 31;
    int col = (cc < 16) ? (nc0 + cc) : (512 + nc0 + (cc - 16));
    cohStore(p.stack + ((size_t)(b0 + bl) * SROWS) * 1024 + col, 0.0f);
  }
  drainvm();
  __syncthreads();
  unsigned genA = 1, genB = 0;
  barA_arrive(blkA, genA, cg);

  for (int step = 1; step <= TT; ++step) {
    const int anyred = anyredt[step];
    const unsigned gB = ++genB;
    const unsigned gAw = genA, gAn = genA + 1;
    const float4 z4 = make_float4(0.f, 0.f, 0.f, 0.f);

    // ---- pre-wait: buf staging (if changed)
    if (!bufSamet[step]) {
      #pragma unroll
      for (int i = 0; i < 4; ++i) {
        const int r = i * 4 + rq;
        const int bx = buft[step][r];
        float4 v = z4;
        if (bx < LL) v = *(const float4*)(p.seq + ((size_t)(b0 + r) * LL + bx) * 1024 + kb);
        *(float4*)&opAll[r][kb] = v;
      }
    }
    // ---- pre-wait: sp1/sp2 rows with seq/zero provenance (plain loads)
    #pragma unroll
    for (int i = 0; i < 4; ++i) {
      const int r = i * 4 + rq;
      const int s1 = sp1sr[step][r], s2 = sp2sr[step][r];
      if (s1 < LL)
        *(float4*)&opAll[r][512 + kb] = *(const float4*)(p.seq + ((size_t)(b0 + r) * LL + s1) * 1024 + kb);
      else if (s1 == 32)
        *(float4*)&opAll[r][512 + kb] = z4;
      if (s2 < LL)
        *(float4*)&opAll[r][1024 + kb] = *(const float4*)(p.seq + ((size_t)(b0 + r) * LL + s2) * 1024 + kb);
      else if (s2 == 32)
        *(float4*)&opAll[r][1024 + kb] = z4;
    }
    // ---- pre-wait: shift steps write stack row from seq directly
    if (!anyred && t < 128) {
      const int bl = t >> 3, nf = (t & 7) * 2, na = nc0 + nf;
      const int bx = buft[step][bl];
      float2 h2 = make_float2(0.f, 0.f), c2 = make_float2(0.f, 0.f);
      if (bx < LL) {
        const float* sb = p.seq + ((size_t)(b0 + bl) * LL + bx) * 1024;
        h2 = *(const float2*)(sb + na);
        c2 = *(const float2*)(sb + 512 + na);
      }
      float* sr = p.stack + ((size_t)(b0 + bl) * SROWS + step) * 1024;
      cohStore2(sr + na, h2);
      cohStore2(sr + 512 + na, c2);
    }
    // ---- pre-wait: fallback buf values + seq-sourced c-prefetch
    float bhv = 0.f, bcv = 0.f, clv = 0.f, crv = 0.f;
    if (anyred && t < 256) {
      const int n = t & 15, bl = t >> 4, na = nc0 + n;
      int bx = buft[step][bl];
      if (bx < LL) {
        bhv = p.seq[((size_t)(b0 + bl) * LL + bx) * 1024 + na];
        bcv = p.seq[((size_t)(b0 + bl) * LL + bx) * 1024 + 512 + na];
      }
      const int s1 = sp1sr[step][bl], s2 = sp2sr[step][bl];
      if (s1 < LL) clv = p.seq[((size_t)(b0 + bl) * LL + s1) * 1024 + 512 + na];
      if (s2 < LL) crv = p.seq[((size_t)(b0 + bl) * LL + s2) * 1024 + 512 + na];
    }
    bar_wait(blkA, gAw);               // ALWAYS wait (ordering invariant)

    // ---- post-wait: stack-sourced rows (coherent from IC)
    {
      float4 v1r[4], v2r[4];
      int m1[4], m2[4];
      #pragma unroll
      for (int i = 0; i < 4; ++i) {
        const int r = i * 4 + rq;
        m1[i] = (sp1sr[step][r] == 200);
        m2[i] = (sp2sr[step][r] == 200);
        if (m1[i]) v1r[i] = cohLoad4(p.stack + ((size_t)(b0 + r) * SROWS + sp1t[step][r]) * 1024 + kb);
        if (m2[i]) v2r[i] = cohLoad4(p.stack + ((size_t)(b0 + r) * SROWS + sp2t[step][r]) * 1024 + kb);
      }
      #pragma unroll
      for (int i = 0; i < 4; ++i) {
        const int r = i * 4 + rq;
        if (m1[i]) *(float4*)&opAll[r][512 + kb]  = v1r[i];
        if (m2[i]) *(float4*)&opAll[r][1024 + kb] = v2r[i];
      }
    }
    if (anyred && t < 256) {
      const int n = t & 15, bl = t >> 4, na = nc0 + n;
      if (sp1sr[step][bl] == 200)
        clv = cohLoad(p.stack + ((size_t)(b0 + bl) * SROWS + sp1t[step][bl]) * 1024 + 512 + na);
      if (sp2sr[step][bl] == 200)
        crv = cohLoad(p.stack + ((size_t)(b0 + bl) * SROWS + sp2t[step][bl]) * 1024 + 512 + na);
    }
    if (!anyred) drainvm();
    __syncthreads();
    if (!anyred) barA_arrive(blkA, gAn, cg);   // EARLY (after wait: safe)

    // ---- compute: tree on t<256 || tracking on t>=256
    if (t < 256) {
      if (anyred) {
        const int bth = t & 3, cth = (t >> 2) & 15, kth = t >> 6;
        const int g = cth >> 2;
        const float* Um = (kth < 2) ? p.Ul[g] : p.Ur[g];
        const int koff = (kth & 1) * 256;
        const int nb = nc0 + (cth & 3) * 4;
        const float* w0 = Um + (size_t)(nb    ) * 512 + koff;
        const float* w1 = Um + (size_t)(nb + 1) * 512 + koff;
        const float* w2 = Um + (size_t)(nb + 2) * 512 + koff;
        const float* w3 = Um + (size_t)(nb + 3) * 512 + koff;
        const int ob = ((kth < 2) ? 512 : 1024) + koff;
        float acc[4][4];
        #pragma unroll
        for (int i = 0; i < 4; ++i)
          #pragma unroll
          for (int j = 0; j < 4; ++j) acc[i][j] = 0.0f;
        #pragma unroll 2
        for (int k4 = 0; k4 < 64; ++k4) {
          const int kk = k4 * 4;
          float4 wv0 = *(const float4*)(w0 + kk);
          float4 wv1 = *(const float4*)(w1 + kk);
          float4 wv2 = *(const float4*)(w2 + kk);
          float4 wv3 = *(const float4*)(w3 + kk);
          #pragma unroll
          for (int bi = 0; bi < 4; ++bi) {
            float4 ov = *(const float4*)&opAll[bi * 4 + bth][ob + kk];
            acc[0][bi] += wv0.x*ov.x + wv0.y*ov.y + wv0.z*ov.z + wv0.w*ov.w;
            acc[1][bi] += wv1.x*ov.x + wv1.y*ov.y + wv1.z*ov.z + wv1.w*ov.w;
            acc[2][bi] += wv2.x*ov.x + wv2.y*ov.y + wv2.z*ov.z + wv2.w*ov.w;
            acc[3][bi] += wv3.x*ov.x + wv3.y*ov.y + wv3.z*ov.z + wv3.w*ov.w;
          }
        }
        const int cc0 = cth * 4;
        #pragma unroll
        for (int ci = 0; ci < 4; ++ci)
          #pragma unroll
          for (int bi = 0; bi < 4; ++bi)
            accS[kth][cc0 + ci][bi * 4 + bth] = acc[ci][bi];
      }
    } else {
      const int tt = t - 256;
      const int q = tt >> 6;
      const int lane = tt & 63;
      const int o = lane >> 3, kth = lane & 7;
      const int r0 = q * 4;
      const float* wrow = p.tWih + (size_t)(o0 + o) * 1536;
      const float* whh  = p.tWhh + (size_t)(o0 + o) * 64;
      const int k0 = kth * 200;
      float tacc[4] = {0.f, 0.f, 0.f, 0.f};
      #pragma unroll 2
      for (int kf = 0; kf < 50; ++kf) {
        const int k = k0 + kf * 4;
        const float* wsrc = (k < 1536) ? (wrow + k) : (whh + (k - 1536));
        float4 wv = *(const float4*)wsrc;
        #pragma unroll
        for (int ri = 0; ri < 4; ++ri) {
          const int r = r0 + ri;
          const float* os = (k < 1536) ? &opAll[r][k] : &th2s[r][k - 1536];
          float4 ov = *(const float4*)os;
          tacc[ri] += wv.x*ov.x + wv.y*ov.y + wv.z*ov.z + wv.w*ov.w;
        }
      }
      #pragma unroll
      for (int ri = 0; ri < 4; ++ri) {
        float v = tacc[ri];
        v += __shfl_xor(v, 1);
        v += __shfl_xor(v, 2);
        v += __shfl_xor(v, 4);
        tacc[ri] = v;
      }
      if (kth == 0) {
        #pragma unroll
        for (int ri = 0; ri < 4; ++ri)
          cohStore(p.tg + (size_t)(b0 + r0 + ri) * 256 + o0 + o, tacc[ri]);
      }
      drainvm();
      if (lane == 0) barB_arrive_lane(blkB, gB, cg);
    }
    __syncthreads();

    // ---- fill barrier-B latency: reduce accS over kth
    if (anyred) {
      #pragma unroll
      for (int rep = 0; rep < 2; ++rep) {
        const int it = t + rep * 512;
        const int cc = it >> 4, bl = it & 15;
        accR[cc][bl] = accS[0][cc][bl] + accS[1][cc][bl]
                     + accS[2][cc][bl] + accS[3][cc][bl];
      }
    }
    bar_wait(blkB, gB);

    // ---- tracking LSTM elementwise (16 b x 64 j; tg loads up-front)
    {
      float gi[2], gf[2], gg[2], go[2];
      int bbp[2], jjp[2];
      #pragma unroll
      for (int rep = 0; rep < 2; ++rep) {
        const int it = t + rep * 512;
        bbp[rep] = it >> 6; jjp[rep] = it & 63;
        const float* tgb = p.tg + (size_t)(b0 + bbp[rep]) * 256;
        gi[rep] = cohLoad(tgb + jjp[rep]);
        gf[rep] = cohLoad(tgb + 64 + jjp[rep]);
        gg[rep] = cohLoad(tgb + 128 + jjp[rep]);
        go[rep] = cohLoad(tgb + 192 + jjp[rep]);
      }
      #pragma unroll
      for (int rep = 0; rep < 2; ++rep) {
        const int b = bbp[rep], j = jjp[rep];
        float c2 = sigm(gf[rep] + tbsum[64 + j]) * tc2s[b][j]
                 + sigm(gi[rep] + tbsum[j]) * tanh_f(gg[rep] + tbsum[128 + j]);
        float h2 = sigm(go[rep] + tbsum[192 + j]) * tanh_f(c2);
        tc2s[b][j] = c2;
        th2s[b][j] = h2;
      }
    }
    if (anyred) {
      __syncthreads();
      #pragma unroll
      for (int rep = 0; rep < 2; ++rep) {
        const int it = t + rep * 512;
        const int cc = it >> 4, bl = it & 15;
        const float* wr = p.Wx[cc >> 4] + (size_t)(nc0 + (cc & 15)) * 64;
        float x = 0.f;
        #pragma unroll 4
        for (int j4 = 0; j4 < 64; j4 += 4) {
          float4 wv = *(const float4*)(wr + j4);
          float4 xv = *(const float4*)&th2s[bl][j4];
          x += wv.x*xv.x + wv.y*xv.y + wv.z*xv.z + wv.w*xv.w;
        }
        xS[cc][bl] = x;
      }
      __syncthreads();
      if (t < 256) {
        const int n = t & 15, bl = t >> 4, na = nc0 + n;
        float h, c;
        if (redt[step][bl]) {
          float pre[4];
          #pragma unroll
          for (int g = 0; g < 4; ++g) {
            const int cc = g * 16 + n;
            pre[g] = accR[cc][bl] + xS[cc][bl] + biasS[g][n];
          }
          float iv = sigm(pre[0]), ov = sigm(pre[1]);
          float fv = sigm(pre[2]), uv = tanh_f(pre[3]);
          c = iv * uv + fv * (clv + crv);
          h = ov * tanh_f(c);
        } else { h = bhv; c = bcv; }
        float* sr = p.stack + ((size_t)(b0 + bl) * SROWS + step) * 1024;
        cohStore(sr + na, h);
        cohStore(sr + 512 + na, c);
        if (step == TT) p.out[(size_t)(b0 + bl) * 512 + na] = h;
        drainvm();
      }
      __syncthreads();
      barA_arrive(blkA, gAn, cg);
    }
    genA = gAn;
  }
}

extern "C" void kernel_launch(void* const* d_in, const int* in_sizes, int n_in,
                              void* d_out, int out_size, void* d_ws, size_t ws_size,
                              hipStream_t stream) {
  Params p;
  p.seq   = (const float*)d_in[0];
  p.trans = (const int*)d_in[1];
  p.Wx[0] = (const float*)d_in[2];   // W_i
  p.Wx[1] = (const float*)d_in[4];   // W_o
  p.Wx[2] = (const float*)d_in[4];   // W_o  (ref bug: f-gate uses W_o)
  p.Wx[3] = (const float*)d_in[5];   // W_u
  p.Ul[0] = (const float*)d_in[6];  p.Ur[0] = (const float*)d_in[7];    // i
  p.Ul[1] = (const float*)d_in[10]; p.Ur[1] = (const float*)d_in[11];   // o
  p.Ul[2] = (const float*)d_in[8];  p.Ur[2] = (const float*)d_in[9];    // f
  p.Ul[3] = (const float*)d_in[12]; p.Ur[3] = (const float*)d_in[13];   // u
  p.bias[0] = (const float*)d_in[14];  // b_i
  p.bias[1] = (const float*)d_in[16];  // b_o
  p.bias[2] = (const float*)d_in[15];  // b_f
  p.bias[3] = (const float*)d_in[17];  // b_u
  p.tWih = (const float*)d_in[18];
  p.tWhh = (const float*)d_in[19];
  p.tbih = (const float*)d_in[20];
  p.tbhh = (const float*)d_in[21];
  p.th0  = (const float*)d_in[22];
  p.tc0  = (const float*)d_in[23];

  float* ws = (float*)d_ws;
  size_t off = 0;
  p.stack = ws + off; off += (size_t)NB * SROWS * 1024;  // 33.5 MB
  p.tg    = ws + off; off += (size_t)NB * 256;           // 128 KB
  unsigned* barmem = (unsigned*)(ws + off); off += 4096; // 16 KB
  if (off * sizeof(float) > ws_size) return;
  p.bm  = barmem;
  p.out = (float*)d_out;

  hipMemsetAsync(barmem, 0, 4096 * sizeof(unsigned), stream);

  void* args[] = { &p };
  hipError_t e = hipLaunchCooperativeKernel((void*)spinn_kernel, dim3(NWG), dim3(NTH),
                                            args, 0, stream);
  if (e != hipSuccess) {
    (void)hipGetLastError();
    spinn_kernel<<<dim3(NWG), dim3(NTH), 0, stream>>>(p);
  }
}

// Round 16
// 735.537 us; speedup vs baseline: 1.4673x; 1.4673x over previous
//
#include <hip/hip_runtime.h>

// SPINN v16 = v12 (champion structure) with both matmuls moved to MFMA
// (mfma_f32_16x16x32_f16). Weights pre-converted once to f16 fragment order
// in workspace (h(hi,i)=hi*8+i; A/B layouts are symmetric so any consistent
// k-bijection is correct; C/D = col lane&15, row (lane>>4)*4+reg, HW-verified).
// opAll staged as f16 -> B-frag = 1 ds_read_b128. Tree: waves 0-3, 1 gate
// M-tile x 32 K-steps each -> accR. Tracking: wave 7 alone, 50 K-steps,
// publishes tg from D regs -> early per-WG barrier-B arrival. fp32 kept for
// recurrent c-path, gates, LSTM state, x@W. Barrier protocol = v12 (proven).

typedef _Float16 f16;
typedef f16 f16x8 __attribute__((ext_vector_type(8)));
typedef float f32x4 __attribute__((ext_vector_type(4)));

constexpr int NB  = 128;
constexpr int LL  = 32;
constexpr int TT  = 63;
constexpr int NWG = 256;
constexpr int NTH = 512;
constexpr int SROWS = 64;

struct Params {
  const float* seq; const int* trans;
  const float* Wx[4];              // i,o,f,u ; Wx[2]==W_o (ref bug kept)
  const float* Ul[4]; const float* Ur[4];
  const float* bias[4];            // b_i, b_o, b_f, b_u
  const float* tWih; const float* tWhh; const float* tbih; const float* tbhh;
  const float* th0; const float* tc0;
  float* stack; float* tg;
  f16* wU; f16* wT;
  unsigned* bm;
  float* out;
};

__device__ __forceinline__ float sigm(float x) { return 1.0f / (1.0f + __expf(-x)); }
__device__ __forceinline__ float tanh_f(float x) {
  x = fminf(fmaxf(x, -15.0f), 15.0f);
  float e = __expf(2.0f * x);
  return (e - 1.0f) / (e + 1.0f);
}
__device__ __forceinline__ float cohLoad(const float* a) {
  return __hip_atomic_load(const_cast<float*>(a), __ATOMIC_RELAXED, __HIP_MEMORY_SCOPE_AGENT);
}
__device__ __forceinline__ float4 cohLoad4(const float* a) {
  union { unsigned long long u[2]; float4 f; } r;
  const unsigned long long* p64 = (const unsigned long long*)a;
  r.u[0] = __hip_atomic_load(const_cast<unsigned long long*>(p64),
                             __ATOMIC_RELAXED, __HIP_MEMORY_SCOPE_AGENT);
  r.u[1] = __hip_atomic_load(const_cast<unsigned long long*>(p64 + 1),
                             __ATOMIC_RELAXED, __HIP_MEMORY_SCOPE_AGENT);
  return r.f;
}
__device__ __forceinline__ void cohStore(float* a, float v) {
  __hip_atomic_store(a, v, __ATOMIC_RELAXED, __HIP_MEMORY_SCOPE_AGENT);
}
__device__ __forceinline__ void cohStore2(float* a, float2 v) {
  union { float2 f; unsigned long long u; } r; r.f = v;
  __hip_atomic_store((unsigned long long*)a, r.u, __ATOMIC_RELAXED,
                     __HIP_MEMORY_SCOPE_AGENT);
}
__device__ __forceinline__ void drainvm() {
  asm volatile("s_waitcnt vmcnt(0)" ::: "memory");
}
__device__ __forceinline__ unsigned relAdd(unsigned* a) {
  return __hip_atomic_fetch_add(a, 1u, __ATOMIC_RELAXED, __HIP_MEMORY_SCOPE_AGENT) + 1u;
}
__device__ __forceinline__ void flagMax(unsigned* f, unsigned gen) {
  __hip_atomic_fetch_max(f, gen, __ATOMIC_RELAXED, __HIP_MEMORY_SCOPE_AGENT);
}
// per-WG arrival: 4 sublines x 8 + root x 4 + flag (word 160)
__device__ __forceinline__ void bar_arrive_any(unsigned* blk, unsigned gen, int l) {
  unsigned a = relAdd(blk + (l & 3) * 32);
  if (a == gen * 8u) {
    unsigned r = relAdd(blk + 128);
    if (r == gen * 4u) flagMax(blk + 160, gen);
  }
}
__device__ __forceinline__ void barA_arrive(unsigned* blk, unsigned gen, int l) {
  if (threadIdx.x == 0) bar_arrive_any(blk, gen, l);
}
__device__ __forceinline__ void bar_wait(unsigned* blk, unsigned gen) {
  if (threadIdx.x == 0) {
    while (__hip_atomic_load(blk + 160, __ATOMIC_RELAXED, __HIP_MEMORY_SCOPE_AGENT) < gen)
      __builtin_amdgcn_s_sleep(1);
  }
  __syncthreads();
}

__launch_bounds__(NTH)
__global__ void spinn_kernel(Params p) {
  const int w = blockIdx.x;
  const int t = threadIdx.x;
  const int cg  = w & 31;
  const int bgp = w >> 5;
  const int b0  = bgp * 16;
  const int nc0 = cg * 16;
  const int o0  = cg * 8;

  unsigned* blkA = p.bm + (size_t)bgp * 512;
  unsigned* blkB = blkA + 256;
  f16* wUcg = p.wU + (size_t)cg * 65536;   // [g][ks][lane][8]
  f16* wTcg = p.wT + (size_t)cg * 25600;   // [ks][lane][8]

  __shared__ f16   opAllh[16][1544];   // [b][ buf(512) | sp1h(512) | sp2h(512) ]
  __shared__ float th2s[16][68];
  __shared__ f16   th2h[16][72];
  __shared__ float tc2s[16][68];
  __shared__ float accR[64][17];       // tree MFMA result [cc][b]
  __shared__ float xS[64][17];
  __shared__ float tbsum[256];
  __shared__ float biasS[4][16];
  __shared__ unsigned char sp1t[TT + 1][16], sp2t[TT + 1][16];
  __shared__ unsigned char buft[TT + 1][16], redt[TT + 1][16];
  __shared__ int anyredt[TT + 1];
  __shared__ int bufSamet[TT + 1];
  __shared__ unsigned char qstkS[16][40];

  const int rq = t >> 7;            // staging row quarter
  const int kb = (t & 127) * 4;     // staging float4 K offset

  // ---- prologue: scalars / state
  if (t < 256) tbsum[t] = p.tbih[t] + p.tbhh[t];
  if (t < 64) biasS[t >> 4][t & 15] = p.bias[t >> 4][nc0 + (t & 15)];
  for (int i = t; i < 1024; i += NTH) {
    float h0 = p.th0[(size_t)(b0 + (i >> 6)) * 64 + (i & 63)];
    th2s[i >> 6][i & 63] = h0;
    th2h[i >> 6][i & 63] = (f16)h0;
    tc2s[i >> 6][i & 63] = p.tc0[(size_t)(b0 + (i >> 6)) * 64 + (i & 63)];
  }
  // ---- prologue: weight conversion to f16 fragment order (own cg slice)
  for (int s = t; s < 8192; s += NTH) {             // tree: (g, ks, lane)
    int g = s >> 11, ks = (s >> 6) & 31, l = s & 63;
    int m = l & 15, hi = l >> 4;
    f16x8 v;
    #pragma unroll
    for (int i = 0; i < 8; ++i) {
      int k = ks * 32 + hi * 8 + i;
      const float* U = (k < 512) ? p.Ul[g] : p.Ur[g];
      v[i] = (f16)U[(size_t)(nc0 + m) * 512 + (k & 511)];
    }
    *(f16x8*)(wUcg + (size_t)s * 8) = v;
  }
  for (int s = t; s < 3200; s += NTH) {             // tracking: (ks, lane)
    int ks = s >> 6, l = s & 63;
    int m = l & 15, hi = l >> 4;
    f16x8 v = {(f16)0, (f16)0, (f16)0, (f16)0, (f16)0, (f16)0, (f16)0, (f16)0};
    if (m < 8) {
      int row = o0 + m;
      #pragma unroll
      for (int i = 0; i < 8; ++i) {
        int k = ks * 32 + hi * 8 + i;
        v[i] = (f16)((k < 1536) ? p.tWih[(size_t)row * 1536 + k]
                                : p.tWhh[(size_t)row * 64 + (k - 1536)]);
      }
    }
    *(f16x8*)(wTcg + (size_t)s * 8) = v;
  }
  // ---- prologue: schedule sim for our 16 b
  if (t < 16) {
    buft[0][t] = 255;
    int bl = t, qn = 0, bp = 0;
    for (int s = 1; s <= TT; ++s) {
      int mask = p.trans[(size_t)(b0 + bl) * TT + (s - 1)];
      int s1 = (qn >= 1) ? qstkS[bl][qn - 1] : 0;
      int s2 = (qn >= 2) ? qstkS[bl][qn - 2] : 0;
      int rd = (mask == 1);
      sp1t[s][bl] = (unsigned char)s1;
      sp2t[s][bl] = (unsigned char)s2;
      redt[s][bl] = (unsigned char)rd;
      buft[s][bl] = (unsigned char)((bp < LL) ? bp : LL);
      int qn2 = rd ? (qn - 2) : qn;
      qstkS[bl][qn2] = (unsigned char)s;
      qn = qn2 + 1;
      bp += rd ? 0 : 1;
    }
  }
  __syncthreads();
  if (t == 0) {
    for (int s = 1; s <= TT; ++s) {
      int a = 0, same = 1;
      for (int bl = 0; bl < 16; ++bl) {
        a |= redt[s][bl];
        same &= (buft[s][bl] == buft[s - 1][bl]);
      }
      anyredt[s] = a;
      bufSamet[s] = same;
    }
  }
  // zero our 32-col slice of stack row 0 for our 16 b
  {
    int bl = t >> 5, cc = t & 31;
    int col = (cc < 16) ? (nc0 + cc) : (512 + nc0 + (cc - 16));
    cohStore(p.stack + ((size_t)(b0 + bl) * SROWS) * 1024 + col, 0.0f);
  }
  drainvm();
  __syncthreads();
  unsigned genA = 1, genB = 0;
  barA_arrive(blkA, genA, cg);

  for (int step = 1; step <= TT; ++step) {
    const int anyred = anyredt[step];
    const unsigned gB = ++genB;
    const unsigned gAw = genA, gAn = genA + 1;

    // ---- pre-wait: seq staging (if buf changed), fp32 -> f16
    if (!bufSamet[step]) {
      #pragma unroll
      for (int i = 0; i < 4; ++i) {
        const int r = i * 4 + rq;
        const int bx = buft[step][r];
        float4 v = make_float4(0.f, 0.f, 0.f, 0.f);
        if (bx < LL) v = *(const float4*)(p.seq + ((size_t)(b0 + r) * LL + bx) * 1024 + kb);
        f16* d = &opAllh[r][kb];
        d[0] = (f16)v.x; d[1] = (f16)v.y; d[2] = (f16)v.z; d[3] = (f16)v.w;
      }
    }
    // ---- pre-wait: shift steps write stack row from seq directly (fp32)
    if (!anyred && t < 128) {
      const int bl = t >> 3, nf = (t & 7) * 2, na = nc0 + nf;
      const int bx = buft[step][bl];
      float2 h2 = make_float2(0.f, 0.f), c2 = make_float2(0.f, 0.f);
      if (bx < LL) {
        const float* sb = p.seq + ((size_t)(b0 + bl) * LL + bx) * 1024;
        h2 = *(const float2*)(sb + na);
        c2 = *(const float2*)(sb + 512 + na);
      }
      float* sr = p.stack + ((size_t)(b0 + bl) * SROWS + step) * 1024;
      cohStore2(sr + na, h2);
      cohStore2(sr + 512 + na, c2);
    }
    float bhv = 0.f, bcv = 0.f, clv = 0.f, crv = 0.f;
    if (anyred && t < 256) {
      const int n = t & 15, bl = t >> 4, na = nc0 + n;
      int bx = buft[step][bl];
      if (bx < LL) {
        bhv = p.seq[((size_t)(b0 + bl) * LL + bx) * 1024 + na];
        bcv = p.seq[((size_t)(b0 + bl) * LL + bx) * 1024 + 512 + na];
      }
    }
    bar_wait(blkA, gAw);               // prev-step stack rows visible

    // ---- stack staging: cohLoad4 -> f16 -> LDS
    {
      float4 v1r[4], v2r[4];
      #pragma unroll
      for (int i = 0; i < 4; ++i) {
        const int r = i * 4 + rq;
        v1r[i] = cohLoad4(p.stack + ((size_t)(b0 + r) * SROWS + sp1t[step][r]) * 1024 + kb);
        v2r[i] = cohLoad4(p.stack + ((size_t)(b0 + r) * SROWS + sp2t[step][r]) * 1024 + kb);
      }
      #pragma unroll
      for (int i = 0; i < 4; ++i) {
        const int r = i * 4 + rq;
        f16* d1 = &opAllh[r][512 + kb];
        d1[0] = (f16)v1r[i].x; d1[1] = (f16)v1r[i].y; d1[2] = (f16)v1r[i].z; d1[3] = (f16)v1r[i].w;
        f16* d2 = &opAllh[r][1024 + kb];
        d2[0] = (f16)v2r[i].x; d2[1] = (f16)v2r[i].y; d2[2] = (f16)v2r[i].z; d2[3] = (f16)v2r[i].w;
      }
    }
    if (anyred && t < 256) {
      const int n = t & 15, bl = t >> 4, na = nc0 + n;
      clv = cohLoad(p.stack + ((size_t)(b0 + bl) * SROWS + sp1t[step][bl]) * 1024 + 512 + na);
      crv = cohLoad(p.stack + ((size_t)(b0 + bl) * SROWS + sp2t[step][bl]) * 1024 + 512 + na);
    }
    if (!anyred) drainvm();
    __syncthreads();
    if (!anyred) barA_arrive(blkA, gAn, cg);   // EARLY (after wait: safe)

    // ---- compute: tree MFMA on waves 0-3 || tracking MFMA on wave 7
    if (t < 256) {
      if (anyred) {
        const int g = t >> 6;            // M-tile = gate
        const int lane = t & 63;
        const int m15 = lane & 15, hi = lane >> 4;
        const f16* aBase = wUcg + (size_t)g * 32 * 512;   // 32 ks * 64 lanes * 8
        f32x4 acc = {0.f, 0.f, 0.f, 0.f};
        #pragma unroll 4
        for (int ks = 0; ks < 32; ++ks) {
          f16x8 a = *(const f16x8*)(aBase + ((size_t)ks * 64 + lane) * 8);
          f16x8 b = *(const f16x8*)&opAllh[m15][512 + ks * 32 + hi * 8];
          acc = __builtin_amdgcn_mfma_f32_16x16x32_f16(a, b, acc, 0, 0, 0);
        }
        #pragma unroll
        for (int r = 0; r < 4; ++r)
          accR[g * 16 + hi * 4 + r][m15] = acc[r];
      }
    } else if (t >= 448) {
      const int lane = t & 63;
      const int m15 = lane & 15, hi = lane >> 4;
      f32x4 acc = {0.f, 0.f, 0.f, 0.f};
      #pragma unroll 2
      for (int ks = 0; ks < 48; ++ks) {
        f16x8 a = *(const f16x8*)(wTcg + ((size_t)ks * 64 + lane) * 8);
        f16x8 b = *(const f16x8*)&opAllh[m15][ks * 32 + hi * 8];
        acc = __builtin_amdgcn_mfma_f32_16x16x32_f16(a, b, acc, 0, 0, 0);
      }
      #pragma unroll
      for (int ks = 48; ks < 50; ++ks) {
        f16x8 a = *(const f16x8*)(wTcg + ((size_t)ks * 64 + lane) * 8);
        f16x8 b = *(const f16x8*)&th2h[m15][(ks - 48) * 32 + hi * 8];
        acc = __builtin_amdgcn_mfma_f32_16x16x32_f16(a, b, acc, 0, 0, 0);
      }
      if (hi < 2) {
        #pragma unroll
        for (int r = 0; r < 4; ++r)
          cohStore(p.tg + (size_t)(b0 + m15) * 256 + o0 + hi * 4 + r, acc[r]);
      }
      drainvm();                         // wave-level: tg stores -> IC
      if (lane == 0) bar_arrive_any(blkB, gB, cg);   // EARLY per-WG arrival
    }
    bar_wait(blkB, gB);                  // tg of whole set visible

    // ---- tracking LSTM elementwise (16 b x 64 j; tg loads up-front)
    {
      float gi[2], gf[2], gg[2], go[2];
      int bbp[2], jjp[2];
      #pragma unroll
      for (int rep = 0; rep < 2; ++rep) {
        const int it = t + rep * 512;
        bbp[rep] = it >> 6; jjp[rep] = it & 63;
        const float* tgb = p.tg + (size_t)(b0 + bbp[rep]) * 256;
        gi[rep] = cohLoad(tgb + jjp[rep]);
        gf[rep] = cohLoad(tgb + 64 + jjp[rep]);
        gg[rep] = cohLoad(tgb + 128 + jjp[rep]);
        go[rep] = cohLoad(tgb + 192 + jjp[rep]);
      }
      #pragma unroll
      for (int rep = 0; rep < 2; ++rep) {
        const int b = bbp[rep], j = jjp[rep];
        float c2 = sigm(gf[rep] + tbsum[64 + j]) * tc2s[b][j]
                 + sigm(gi[rep] + tbsum[j]) * tanh_f(gg[rep] + tbsum[128 + j]);
        float h2 = sigm(go[rep] + tbsum[192 + j]) * tanh_f(c2);
        tc2s[b][j] = c2;
        th2s[b][j] = h2;
        th2h[b][j] = (f16)h2;
      }
    }
    if (anyred) {
      __syncthreads();
      // x@W: 64 cc x 16 b, K=64 (fp32 VALU, weights L2-hot)
      #pragma unroll
      for (int rep = 0; rep < 2; ++rep) {
        const int it = t + rep * 512;
        const int cc = it >> 4, bl = it & 15;
        const float* wr = p.Wx[cc >> 4] + (size_t)(nc0 + (cc & 15)) * 64;
        float x = 0.f;
        #pragma unroll 4
        for (int j4 = 0; j4 < 64; j4 += 4) {
          float4 wv = *(const float4*)(wr + j4);
          float4 xv = *(const float4*)&th2s[bl][j4];
          x += wv.x*xv.x + wv.y*xv.y + wv.z*xv.z + wv.w*xv.w;
        }
        xS[cc][bl] = x;
      }
      __syncthreads();
      // gates + stack row write
      if (t < 256) {
        const int n = t & 15, bl = t >> 4, na = nc0 + n;
        float h, c;
        if (redt[step][bl]) {
          float pre[4];
          #pragma unroll
          for (int g = 0; g < 4; ++g) {
            const int cc = g * 16 + n;
            pre[g] = accR[cc][bl] + xS[cc][bl] + biasS[g][n];
          }
          float iv = sigm(pre[0]), ov = sigm(pre[1]);
          float fv = sigm(pre[2]), uv = tanh_f(pre[3]);
          c = iv * uv + fv * (clv + crv);
          h = ov * tanh_f(c);
        } else { h = bhv; c = bcv; }
        float* sr = p.stack + ((size_t)(b0 + bl) * SROWS + step) * 1024;
        cohStore(sr + na, h);
        cohStore(sr + 512 + na, c);
        if (step == TT) p.out[(size_t)(b0 + bl) * 512 + na] = h;
        drainvm();
      }
      __syncthreads();
      barA_arrive(blkA, gAn, cg);
    }
    genA = gAn;
  }
}

extern "C" void kernel_launch(void* const* d_in, const int* in_sizes, int n_in,
                              void* d_out, int out_size, void* d_ws, size_t ws_size,
                              hipStream_t stream) {
  Params p;
  p.seq   = (const float*)d_in[0];
  p.trans = (const int*)d_in[1];
  p.Wx[0] = (const float*)d_in[2];   // W_i
  p.Wx[1] = (const float*)d_in[4];   // W_o
  p.Wx[2] = (const float*)d_in[4];   // W_o  (ref bug: f-gate uses W_o)
  p.Wx[3] = (const float*)d_in[5];   // W_u
  p.Ul[0] = (const float*)d_in[6];  p.Ur[0] = (const float*)d_in[7];    // i
  p.Ul[1] = (const float*)d_in[10]; p.Ur[1] = (const float*)d_in[11];   // o
  p.Ul[2] = (const float*)d_in[8];  p.Ur[2] = (const float*)d_in[9];    // f
  p.Ul[3] = (const float*)d_in[12]; p.Ur[3] = (const float*)d_in[13];   // u
  p.bias[0] = (const float*)d_in[14];  // b_i
  p.bias[1] = (const float*)d_in[16];  // b_o
  p.bias[2] = (const float*)d_in[15];  // b_f
  p.bias[3] = (const float*)d_in[17];  // b_u
  p.tWih = (const float*)d_in[18];
  p.tWhh = (const float*)d_in[19];
  p.tbih = (const float*)d_in[20];
  p.tbhh = (const float*)d_in[21];
  p.th0  = (const float*)d_in[22];
  p.tc0  = (const float*)d_in[23];

  float* ws = (float*)d_ws;
  size_t off = 0;
  p.stack = ws + off; off += (size_t)NB * SROWS * 1024;    // 33.5 MB
  p.tg    = ws + off; off += (size_t)NB * 256;             // 128 KB
  unsigned* barmem = (unsigned*)(ws + off); off += 4096;   // 16 KB
  p.wU = (f16*)(ws + off); off += (size_t)32 * 65536 / 2;  // 4 MB f16
  p.wT = (f16*)(ws + off); off += (size_t)32 * 25600 / 2;  // 1.6 MB f16
  if (off * sizeof(float) > ws_size) return;
  p.bm  = barmem;
  p.out = (float*)d_out;

  hipMemsetAsync(barmem, 0, 4096 * sizeof(unsigned), stream);

  void* args[] = { &p };
  hipError_t e = hipLaunchCooperativeKernel((void*)spinn_kernel, dim3(NWG), dim3(NTH),
                                            args, 0, stream);
  if (e != hipSuccess) {
    (void)hipGetLastError();
    spinn_kernel<<<dim3(NWG), dim3(NTH), 0, stream>>>(p);
  }
}